// Round 1
// baseline (71.123 us; speedup 1.0000x reference)
//
#include <hip/hip_runtime.h>

// Daubechies-4 (db2) synthesis filter taps, f32
#define H_0 0.48296291314469025f
#define H_1 0.8365163037378079f
#define H_2 0.22414386804201336f
#define H_3 (-0.12940952255092145f)
#define G_0 (-0.12940952255092145f)
#define G_1 (-0.22414386804201336f)
#define G_2 0.8365163037378079f
#define G_3 (-0.48296291314469025f)

// One inverse-synthesis pass along rows (axis 0).
// Input wt(i,c): top-left S2 x S2 quadrant comes from `sub` (previous level
// result, leading dim ldsub) when sub != nullptr; everything else from x.
// Output t is S x S with leading dim ldt.
// t[2m][c]   = H0*L[m] + H2*L[m-1] + G0*Hi[m] + G2*Hi[m-1]
// t[2m+1][c] = H1*L[m] + H3*L[m-1] + G1*Hi[m] + G3*Hi[m-1]
// where L[i] = wt[i][c] (i<S2), Hi[i] = wt[S2+i][c], indices mod S2.
__global__ void iwt_rows(const float* __restrict__ x,
                         const float* __restrict__ sub,
                         float* __restrict__ t,
                         int S, int ldx, int ldsub, int ldt) {
    const int c = blockIdx.x * blockDim.x + threadIdx.x;
    const int m = blockIdx.y;
    const int S2 = S >> 1;
    if (c >= S) return;
    const int mm = (m == 0) ? (S2 - 1) : (m - 1);

    const bool colSub = (sub != nullptr) && (c < S2);  // m, mm are always < S2
    const float L0 = colSub ? sub[m  * ldsub + c] : x[m  * ldx + c];
    const float L1 = colSub ? sub[mm * ldsub + c] : x[mm * ldx + c];
    // High half rows (index >= S2) never overlap the sub quadrant.
    const float Ha = x[(S2 + m)  * ldx + c];
    const float Hb = x[(S2 + mm) * ldx + c];

    t[(2 * m)     * ldt + c] = H_0 * L0 + H_2 * L1 + G_0 * Ha + G_2 * Hb;
    t[(2 * m + 1) * ldt + c] = H_1 * L0 + H_3 * L1 + G_1 * Ha + G_3 * Hb;
}

// One inverse-synthesis pass along columns (axis 1).
// out[r][2m], out[r][2m+1] from t[r][m], t[r][(m-1)%S2], t[r][S2+m], t[r][S2+(m-1)%S2].
__global__ void iwt_cols(const float* __restrict__ t,
                         float* __restrict__ out,
                         int S, int ldt, int ldo) {
    const int m = blockIdx.x * blockDim.x + threadIdx.x;
    const int r = blockIdx.y;
    const int S2 = S >> 1;
    if (m >= S2) return;
    const int mm = (m == 0) ? (S2 - 1) : (m - 1);

    const float* row = t + (size_t)r * ldt;
    const float L0 = row[m];
    const float L1 = row[mm];
    const float Ha = row[S2 + m];
    const float Hb = row[S2 + mm];

    const float even = H_0 * L0 + H_2 * L1 + G_0 * Ha + G_2 * Hb;
    const float odd  = H_1 * L0 + H_3 * L1 + G_1 * Ha + G_3 * Hb;

    // Adjacent pair -> 8B-aligned float2 store (r*ldo even, 2m even).
    *reinterpret_cast<float2*>(out + (size_t)r * ldo + 2 * m) = make_float2(even, odd);
}

extern "C" void kernel_launch(void* const* d_in, const int* in_sizes, int n_in,
                              void* d_out, int out_size, void* d_ws, size_t ws_size,
                              hipStream_t stream) {
    const float* x = (const float*)d_in[0];   // (1, 4096, 4096) f32
    // d_in[1] = mask, d_in[2] = b : unused by the reference computation
    // d_in[3] = wavSplit (4x4 int32) -> levels = 3 (static)
    float* out = (float*)d_out;               // 4096 x 4096 f32
    float* t   = (float*)d_ws;                // temp, up to 4096*4096 f32 = 64 MB

    const int N = 4096;
    const int BS = 256;

    // Level sizes: 1024 -> 2048 -> 4096. Each level: rows pass into t (ld S),
    // cols pass into top-left SxS of out (ld 4096). Next level reads that
    // region as `sub`.
    // Level 1 (S=1024): no sub.
    {
        const int S = 1024, S2 = S >> 1;
        iwt_rows<<<dim3(S / BS, S2), BS, 0, stream>>>(x, nullptr, t, S, N, 0, S);
        iwt_cols<<<dim3((S2 + BS - 1) / BS, S), BS, 0, stream>>>(t, out, S, S, N);
    }
    // Level 2 (S=2048): sub = out[:1024,:1024] (ld 4096).
    {
        const int S = 2048, S2 = S >> 1;
        iwt_rows<<<dim3(S / BS, S2), BS, 0, stream>>>(x, out, t, S, N, N, S);
        iwt_cols<<<dim3((S2 + BS - 1) / BS, S), BS, 0, stream>>>(t, out, S, S, N);
    }
    // Level 3 (S=4096): sub = out[:2048,:2048] (ld 4096).
    {
        const int S = 4096, S2 = S >> 1;
        iwt_rows<<<dim3(S / BS, S2), BS, 0, stream>>>(x, out, t, S, N, N, S);
        iwt_cols<<<dim3((S2 + BS - 1) / BS, S), BS, 0, stream>>>(t, out, S, S, N);
    }
}

// Round 3
// 54.471 us; speedup vs baseline: 1.3057x; 1.3057x over previous
//
#include <hip/hip_runtime.h>

// Daubechies-4 (db2) synthesis filter taps, f32
#define H_0 0.48296291314469025f
#define H_1 0.8365163037378079f
#define H_2 0.22414386804201336f
#define H_3 (-0.12940952255092145f)
#define G_0 (-0.12940952255092145f)
#define G_1 (-0.22414386804201336f)
#define G_2 0.8365163037378079f
#define G_3 (-0.48296291314469025f)

// Fused one-level inverse db2 (rows pass + cols pass) through LDS.
// Output tile TH x TW per block. The intermediate t (row-pass result) for
// this tile needs rows [r0, r0+TH) and, per column half, cols
// [n0-1, n0+TW/2) (the -1 halo carries the circular wrap of the cols pass).
// t itself is computed from input rows m, m-1, S2+m, S2+m-1 (wrap baked in).
//
// Input value at (gr, gc): top-left S2 x S2 quadrant comes from `sub`
// (previous level result) when sub != nullptr, else from x. Rows-pass L
// reads always have gr < S2, so the sub test reduces to (col < S2).
constexpr int TH = 64;
constexpr int TW = 64;
constexpr int NC = TW + 2;  // 66 = 33 low cols + 33 high cols (each with -1 halo)

__global__ __launch_bounds__(256) void iwt_fused(
    const float* __restrict__ x, int ldx,
    const float* __restrict__ sub, int ldsub,
    float* __restrict__ out, int ldo,
    int S, int tilesX) {
    const int S2 = S >> 1;
    const int tx = blockIdx.x % tilesX;
    const int ty = blockIdx.x / tilesX;
    const int r0 = ty * TH;       // output row start
    const int c0 = tx * TW;       // output col start
    const int m0 = r0 >> 1;       // first row-pass index (TH/2 of them)
    const int n0 = c0 >> 1;       // first col-pass index (TW/2 of them)

    __shared__ float tl[TH][NC];

    const int tid = threadIdx.x;
    const bool hasSub = (sub != nullptr);

    // Step 1: rows pass -> LDS. Tasks: (mi, ci), mi in [0,TH/2), ci in [0,NC).
    // ci < NC/2: low column gc = wrap(n0-1+ci); ci >= NC/2: high column S2+gc.
    for (int idx = tid; idx < (TH / 2) * NC; idx += 256) {
        const int mi = idx / NC;
        const int ci = idx - mi * NC;
        const int q = (ci < NC / 2) ? ci : ci - NC / 2;
        int gc = n0 - 1 + q;
        if (gc < 0) gc += S2;                 // circular wrap (tx == 0, q == 0)
        const bool colIsHigh = (ci >= NC / 2);
        const int col = colIsHigh ? (gc + S2) : gc;

        const int m = m0 + mi;
        int mp = m - 1;
        if (mp < 0) mp = S2 - 1;              // circular wrap (ty == 0, mi == 0)

        float L0, L1;
        if (hasSub && !colIsHigh) {           // gr < S2 and gc < S2 -> sub
            L0 = sub[(size_t)m  * ldsub + col];
            L1 = sub[(size_t)mp * ldsub + col];
        } else {
            L0 = x[(size_t)m  * ldx + col];
            L1 = x[(size_t)mp * ldx + col];
        }
        const float Ha = x[(size_t)(S2 + m)  * ldx + col];  // gr >= S2: always x
        const float Hb = x[(size_t)(S2 + mp) * ldx + col];

        tl[2 * mi][ci]     = H_0 * L0 + H_2 * L1 + G_0 * Ha + G_2 * Hb;
        tl[2 * mi + 1][ci] = H_1 * L0 + H_3 * L1 + G_1 * Ha + G_3 * Hb;
    }
    __syncthreads();

    // Step 2: cols pass from LDS -> global. Tasks: (r, ni), output pair at
    // (r0+r, c0+2ni). n = n0+ni maps to local col ni+1 (low) / NC/2+ni+1 (high),
    // n-1 to ni / NC/2+ni (wrap already baked into the halo column).
    for (int idx = tid; idx < TH * (TW / 2); idx += 256) {
        const int r = idx / (TW / 2);
        const int ni = idx - r * (TW / 2);
        const float L1 = tl[r][ni];
        const float L0 = tl[r][ni + 1];
        const float Hb = tl[r][NC / 2 + ni];
        const float Ha = tl[r][NC / 2 + ni + 1];

        const float even = H_0 * L0 + H_2 * L1 + G_0 * Ha + G_2 * Hb;
        const float odd  = H_1 * L0 + H_3 * L1 + G_1 * Ha + G_3 * Hb;

        *reinterpret_cast<float2*>(&out[(size_t)(r0 + r) * ldo + c0 + 2 * ni]) =
            make_float2(even, odd);
    }
}

extern "C" void kernel_launch(void* const* d_in, const int* in_sizes, int n_in,
                              void* d_out, int out_size, void* d_ws, size_t ws_size,
                              hipStream_t stream) {
    const float* x = (const float*)d_in[0];   // (1, 4096, 4096) f32
    // d_in[1] = mask, d_in[2] = b : unused; d_in[3] = wavSplit -> levels = 3
    float* out = (float*)d_out;               // 4096 x 4096 f32
    float* buf1 = (float*)d_ws;                                 // 1024^2 f32 (4 MB)
    float* buf2 = (float*)((char*)d_ws + ((size_t)16 << 20));   // 2048^2 f32 (16 MB)

    const int N = 4096;

    // Level 1 (S=1024): input = x top-left, no sub; output -> buf1 (ld 1024).
    {
        const int S = 1024, tilesX = S / TW;
        iwt_fused<<<tilesX * (S / TH), 256, 0, stream>>>(
            x, N, nullptr, 0, buf1, S, S, tilesX);
    }
    // Level 2 (S=2048): sub = buf1 (ld 1024); output -> buf2 (ld 2048).
    {
        const int S = 2048, tilesX = S / TW;
        iwt_fused<<<tilesX * (S / TH), 256, 0, stream>>>(
            x, N, buf1, 1024, buf2, S, S, tilesX);
    }
    // Level 3 (S=4096): sub = buf2 (ld 2048); output -> out (ld 4096).
    {
        const int S = 4096, tilesX = S / TW;
        iwt_fused<<<tilesX * (S / TH), 256, 0, stream>>>(
            x, N, buf2, 2048, out, S, N, tilesX);
    }
}

// Round 4
// 48.291 us; speedup vs baseline: 1.4728x; 1.1280x over previous
//
#include <hip/hip_runtime.h>

// Daubechies-4 (db2) synthesis filter taps, f32
#define H_0 0.48296291314469025f
#define H_1 0.8365163037378079f
#define H_2 0.22414386804201336f
#define H_3 (-0.12940952255092145f)
#define G_0 (-0.12940952255092145f)
#define G_1 (-0.22414386804201336f)
#define G_2 0.8365163037378079f
#define G_3 (-0.48296291314469025f)

// Fused one-level inverse db2 (rows pass + cols pass) through LDS.
// Output tile TH x TW per block.
//
// LDS layout (per t-row, stride 72 floats = 288 B, float4-aligned):
//   cols [0,32)   : low-half t columns n0..n0+31
//   col  32       : low halo  t column n0-1 (circularly wrapped)
//   cols [36,68)  : high-half t columns n0..n0+31
//   col  68       : high halo t column n0-1
// Main-body loads/stores are all float4; the halo is 64 scalar tasks.
constexpr int TH = 64;
constexpr int TW = 64;
constexpr int LSTRIDE = 72;
constexpr int LOW_HALO = 32;
constexpr int HIGH_BASE = 36;
constexpr int HIGH_HALO = 68;

__global__ __launch_bounds__(256) void iwt_fused(
    const float* __restrict__ x, int ldx,
    const float* __restrict__ sub, int ldsub,
    float* __restrict__ out, int ldo,
    int S, int tilesX) {
    const int S2 = S >> 1;
    const int tx = blockIdx.x % tilesX;
    const int ty = blockIdx.x / tilesX;
    const int r0 = ty * TH;       // output row start
    const int c0 = tx * TW;       // output col start
    const int m0 = r0 >> 1;       // first row-pass index (TH/2 of them)
    const int n0 = c0 >> 1;       // first col-pass index (TW/2 of them)

    __shared__ float tl[TH * LSTRIDE];

    const int tid = threadIdx.x;
    const bool hasSub = (sub != nullptr);

    // ---- Step 1 main: rows pass -> LDS, float4 granularity.
    // 512 tasks: (mi in [0,32)) x (half in {0,1}) x (q in [0,8)).
    // t[2mi][.] / t[2mi+1][.] from input rows m, m-1, S2+m, S2+m-1 (wrap baked).
#pragma unroll
    for (int k = 0; k < 2; ++k) {
        const int task = tid + 256 * k;
        const int mi = task >> 4;
        const int half = (task >> 3) & 1;
        const int q = task & 7;

        const int m = m0 + mi;
        const int mp = (m == 0) ? (S2 - 1) : (m - 1);
        const int colBase = (half ? S2 : 0) + n0 + 4 * q;

        // sub region is rows<S2 AND cols<S2; L rows are always <S2.
        const bool fromSub = hasSub && (half == 0);
        const float* __restrict__ pL = fromSub ? sub : x;
        const int ldL = fromSub ? ldsub : ldx;

        const float4 L0 = *reinterpret_cast<const float4*>(pL + m  * ldL + colBase);
        const float4 L1 = *reinterpret_cast<const float4*>(pL + mp * ldL + colBase);
        const float4 Ha = *reinterpret_cast<const float4*>(x + (S2 + m)  * ldx + colBase);
        const float4 Hb = *reinterpret_cast<const float4*>(x + (S2 + mp) * ldx + colBase);

        float4 t0, t1;
        t0.x = H_0 * L0.x + H_2 * L1.x + G_0 * Ha.x + G_2 * Hb.x;
        t0.y = H_0 * L0.y + H_2 * L1.y + G_0 * Ha.y + G_2 * Hb.y;
        t0.z = H_0 * L0.z + H_2 * L1.z + G_0 * Ha.z + G_2 * Hb.z;
        t0.w = H_0 * L0.w + H_2 * L1.w + G_0 * Ha.w + G_2 * Hb.w;
        t1.x = H_1 * L0.x + H_3 * L1.x + G_1 * Ha.x + G_3 * Hb.x;
        t1.y = H_1 * L0.y + H_3 * L1.y + G_1 * Ha.y + G_3 * Hb.y;
        t1.z = H_1 * L0.z + H_3 * L1.z + G_1 * Ha.z + G_3 * Hb.z;
        t1.w = H_1 * L0.w + H_3 * L1.w + G_1 * Ha.w + G_3 * Hb.w;

        const int lbase = (half ? HIGH_BASE : 0) + 4 * q;
        *reinterpret_cast<float4*>(&tl[(2 * mi)     * LSTRIDE + lbase]) = t0;
        *reinterpret_cast<float4*>(&tl[(2 * mi + 1) * LSTRIDE + lbase]) = t1;
    }

    // ---- Step 1 halo: t column n0-1 (wrapped), 64 scalar tasks.
    if (tid < TH) {
        const int mi = tid >> 1;
        const int half = tid & 1;
        const int m = m0 + mi;
        const int mp = (m == 0) ? (S2 - 1) : (m - 1);
        int gc = n0 - 1;
        if (gc < 0) gc = S2 - 1;            // circular wrap (tx == 0)
        const int col = (half ? S2 : 0) + gc;

        const bool fromSub = hasSub && (half == 0);
        const float* __restrict__ pL = fromSub ? sub : x;
        const int ldL = fromSub ? ldsub : ldx;

        const float L0 = pL[m  * ldL + col];
        const float L1 = pL[mp * ldL + col];
        const float Ha = x[(S2 + m)  * ldx + col];
        const float Hb = x[(S2 + mp) * ldx + col];

        const int hc = half ? HIGH_HALO : LOW_HALO;
        tl[(2 * mi)     * LSTRIDE + hc] = H_0 * L0 + H_2 * L1 + G_0 * Ha + G_2 * Hb;
        tl[(2 * mi + 1) * LSTRIDE + hc] = H_1 * L0 + H_3 * L1 + G_1 * Ha + G_3 * Hb;
    }
    __syncthreads();

    // ---- Step 2: cols pass from LDS -> global, one float4 (4 outputs) per task.
    // 1024 tasks: r in [0,64) x ni2 in [0,16); outputs at cols c0+4*ni2..+3.
#pragma unroll
    for (int k = 0; k < 4; ++k) {
        const int task = tid + 256 * k;
        const int r = task >> 4;
        const int ni2 = task & 15;
        const float* row = &tl[r * LSTRIDE];
        const int n2 = 2 * ni2;

        const float Lm1 = row[(n2 == 0) ? LOW_HALO : (n2 - 1)];
        const float La  = row[n2];
        const float Lb  = row[n2 + 1];
        const float Hm1 = row[(n2 == 0) ? HIGH_HALO : (HIGH_BASE + n2 - 1)];
        const float Hha = row[HIGH_BASE + n2];
        const float Hhb = row[HIGH_BASE + n2 + 1];

        float4 o;
        o.x = H_0 * La + H_2 * Lm1 + G_0 * Hha + G_2 * Hm1;
        o.y = H_1 * La + H_3 * Lm1 + G_1 * Hha + G_3 * Hm1;
        o.z = H_0 * Lb + H_2 * La  + G_0 * Hhb + G_2 * Hha;
        o.w = H_1 * Lb + H_3 * La  + G_1 * Hhb + G_3 * Hha;

        *reinterpret_cast<float4*>(&out[(size_t)(r0 + r) * ldo + c0 + 4 * ni2]) = o;
    }
}

extern "C" void kernel_launch(void* const* d_in, const int* in_sizes, int n_in,
                              void* d_out, int out_size, void* d_ws, size_t ws_size,
                              hipStream_t stream) {
    const float* x = (const float*)d_in[0];   // (1, 4096, 4096) f32
    // d_in[1] = mask, d_in[2] = b : unused; d_in[3] = wavSplit -> levels = 3
    float* out = (float*)d_out;               // 4096 x 4096 f32
    float* buf1 = (float*)d_ws;                                 // 1024^2 f32 (4 MB)
    float* buf2 = (float*)((char*)d_ws + ((size_t)16 << 20));   // 2048^2 f32 (16 MB)

    const int N = 4096;

    // Level 1 (S=1024): input = x top-left, no sub; output -> buf1 (ld 1024).
    {
        const int S = 1024, tilesX = S / TW;
        iwt_fused<<<tilesX * (S / TH), 256, 0, stream>>>(
            x, N, nullptr, 0, buf1, S, S, tilesX);
    }
    // Level 2 (S=2048): sub = buf1 (ld 1024); output -> buf2 (ld 2048).
    {
        const int S = 2048, tilesX = S / TW;
        iwt_fused<<<tilesX * (S / TH), 256, 0, stream>>>(
            x, N, buf1, 1024, buf2, S, S, tilesX);
    }
    // Level 3 (S=4096): sub = buf2 (ld 2048); output -> out (ld 4096).
    {
        const int S = 4096, tilesX = S / TW;
        iwt_fused<<<tilesX * (S / TH), 256, 0, stream>>>(
            x, N, buf2, 2048, out, S, N, tilesX);
    }
}